// Round 8
// baseline (1591.854 us; speedup 1.0000x reference)
//
#include <hip/hip_runtime.h>
#include <hip/hip_bf16.h>

typedef __hip_bfloat16 bf16;
typedef unsigned short ushort_t;
typedef unsigned int uint_t;
typedef __attribute__((ext_vector_type(8))) short short8;
typedef __attribute__((ext_vector_type(4))) float floatx4;

__device__ __forceinline__ float b2f(bf16 x) { return __bfloat162float(x); }
__device__ __forceinline__ ushort_t f2us(float f) { bf16 h = __float2bfloat16(f); return *(ushort_t*)&h; }
__device__ __forceinline__ float us2f(ushort_t u) { return __uint_as_float(((uint_t)u) << 16); }

constexpr int Bc = 4, Tc = 1024, Dc = 512, Hc = 8, HDc = 64;
constexpr int LCc = 128, MPc = 192;
constexpr float EPSc = 1e-4f;
constexpr int NBT = Bc * Tc;
constexpr long NE = (long)NBT * Dc;
constexpr float NEGB = -1e30f;

__device__ __forceinline__ float wload(const void* p, long i, int f32) {
  return f32 ? ((const float*)p)[i] : b2f(((const bf16*)p)[i]);
}

// ---------------- dtype detector ----------------
__global__ void k_detect(const void* __restrict__ x, int* __restrict__ flag) {
  __shared__ int s[256];
  int t = threadIdx.x;
  const unsigned short* u = (const unsigned short*)x;
  int bad = 0;
  for (int j = t; j < 2048; j += 256) {
    int e = (u[j] >> 7) & 0xFF;
    if (e == 0xFF || e > 0x8F || (e != 0 && e < 0x6F)) bad++;
  }
  s[t] = bad;
  __syncthreads();
  for (int off = 128; off > 0; off >>= 1) { if (t < off) s[t] += s[t + off]; __syncthreads(); }
  if (t == 0) flag[0] = (s[0] > 16) ? 1 : 0;
}

__global__ void k_in(const void* __restrict__ in, float* __restrict__ out, int n,
                     const int* __restrict__ flag) {
  int i = blockIdx.x * 256 + threadIdx.x;
  if (i < n) out[i] = wload(in, i, flag[0]);
}
__global__ void k_out(const float* __restrict__ in, void* __restrict__ out, int n,
                      const int* __restrict__ flag) {
  int i = blockIdx.x * 256 + threadIdx.x;
  if (i >= n) return;
  if (flag[0]) ((float*)out)[i] = in[i];
  else         ((bf16*)out)[i] = __float2bfloat16(in[i]);
}
// weight -> bf16 workspace copy (with scale, e.g. 0.125 folded into Wq)
__global__ void k_w2b(const void* __restrict__ src, long srcoff, ushort_t* __restrict__ dst,
                      int n, float scale, const int* __restrict__ flag) {
  int i = blockIdx.x * 256 + threadIdx.x;
  if (i < n) dst[i] = f2us(wload(src, srcoff + i, flag[0]) * scale);
}

// ---------------- LayerNorm: writes f32 (residual addend) + bf16 (GEMM A) ----------------
__global__ __launch_bounds__(256) void k_ln(const float* __restrict__ x,
    const void* __restrict__ w, const void* __restrict__ bb, long woff,
    float* __restrict__ o, ushort_t* __restrict__ oA, const int* __restrict__ flag) {
  int f32 = flag[0];
  int row = blockIdx.x;
  int t = threadIdx.x;
  const float* xr = x + (long)row * Dc;
  float x0 = xr[t], x1 = xr[t + 256];
  __shared__ float red[256];
  red[t] = x0 + x1;
  __syncthreads();
  for (int off = 128; off > 0; off >>= 1) { if (t < off) red[t] += red[t + off]; __syncthreads(); }
  float mean = red[0] * (1.0f / Dc);
  __syncthreads();
  float d0 = x0 - mean, d1 = x1 - mean;
  red[t] = d0 * d0 + d1 * d1;
  __syncthreads();
  for (int off = 128; off > 0; off >>= 1) { if (t < off) red[t] += red[t + off]; __syncthreads(); }
  float inv = 1.0f / sqrtf(red[0] * (1.0f / Dc) + EPSc);
  float v0 = d0 * inv * wload(w, woff + t, f32)       + wload(bb, woff + t, f32);
  float v1 = d1 * inv * wload(w, woff + t + 256, f32) + wload(bb, woff + t + 256, f32);
  float* orow = o + (long)row * Dc;
  ushort_t* arow = oA + (long)row * Dc;
  orow[t] = v0; orow[t + 256] = v1;
  arow[t] = f2us(v0); arow[t + 256] = f2us(v1);
}

// ---------------- bf16 MFMA GEMM with register-prefetch pipeline ----------------
// BK=64, XOR-swizzled LDS (conflict-free, verified R7: SQ_LDS_BANK_CONFLICT=0).
template<int BM, int BN, bool OBF>
__global__ __launch_bounds__(256) void k_gemm_b(const ushort_t* __restrict__ A, int lda,
    const ushort_t* __restrict__ W, void* __restrict__ C, int ldc,
    const float* __restrict__ addend, float alpha, int K) {
  constexpr int WGM = BM / 64;
  constexpr int WGN = 4 / WGM;
  constexpr int WN = BN / WGN;
  constexpr int NJ = WN / 16;
  constexpr int NA = BM * 8 / 256;
  constexpr int NW = BN * 8 / 256;
  __shared__ ushort_t As[BM * 64];
  __shared__ ushort_t Ws[BN * 64];
  int t = threadIdx.x;
  int m0 = blockIdx.y * BM, n0 = blockIdx.x * BN;
  int lane = t & 63, wv = t >> 6;
  int l15 = lane & 15, quad = lane >> 4;
  int wrow = (WGM == 2) ? (wv >> 1) * 64 : 0;
  int wcol = (WGM == 2) ? (wv & 1) * WN : wv * WN;
  floatx4 acc[4][NJ];
#pragma unroll
  for (int i = 0; i < 4; ++i)
#pragma unroll
    for (int j = 0; j < NJ; ++j) acc[i][j] = 0;
  uint4 ra[NA], rw[NW];
#pragma unroll
  for (int i = 0; i < NA; ++i) { int idx = t + i * 256; int r = idx >> 3, c = idx & 7;
    ra[i] = *(const uint4*)(A + (long)(m0 + r) * lda + c * 8); }
#pragma unroll
  for (int i = 0; i < NW; ++i) { int idx = t + i * 256; int r = idx >> 3, c = idx & 7;
    rw[i] = *(const uint4*)(W + (long)(n0 + r) * K + c * 8); }
  for (int k0 = 0; k0 < K; k0 += 64) {
#pragma unroll
    for (int i = 0; i < NA; ++i) { int idx = t + i * 256; int r = idx >> 3, c = idx & 7;
      *(uint4*)&As[r * 64 + ((c ^ (r & 7)) << 3)] = ra[i]; }
#pragma unroll
    for (int i = 0; i < NW; ++i) { int idx = t + i * 256; int r = idx >> 3, c = idx & 7;
      *(uint4*)&Ws[r * 64 + ((c ^ (r & 7)) << 3)] = rw[i]; }
    __syncthreads();
    int kn = k0 + 64;
    if (kn < K) {
#pragma unroll
      for (int i = 0; i < NA; ++i) { int idx = t + i * 256; int r = idx >> 3, c = idx & 7;
        ra[i] = *(const uint4*)(A + (long)(m0 + r) * lda + kn + c * 8); }
#pragma unroll
      for (int i = 0; i < NW; ++i) { int idx = t + i * 256; int r = idx >> 3, c = idx & 7;
        rw[i] = *(const uint4*)(W + (long)(n0 + r) * K + kn + c * 8); }
    }
#pragma unroll
    for (int half = 0; half < 2; ++half) {
      int sw = ((half * 4 + quad) ^ (l15 & 7)) << 3;
      short8 af[4], bfr[NJ];
#pragma unroll
      for (int i = 0; i < 4; ++i) af[i] = *(short8*)&As[(wrow + i * 16 + l15) * 64 + sw];
#pragma unroll
      for (int j = 0; j < NJ; ++j) bfr[j] = *(short8*)&Ws[(wcol + j * 16 + l15) * 64 + sw];
#pragma unroll
      for (int i = 0; i < 4; ++i)
#pragma unroll
        for (int j = 0; j < NJ; ++j)
          acc[i][j] = __builtin_amdgcn_mfma_f32_16x16x32_bf16(af[i], bfr[j], acc[i][j], 0, 0, 0);
    }
    __syncthreads();
  }
#pragma unroll
  for (int i = 0; i < 4; ++i) {
#pragma unroll
    for (int j = 0; j < NJ; ++j) {
#pragma unroll
      for (int rg = 0; rg < 4; ++rg) {
        int m = m0 + wrow + i * 16 + quad * 4 + rg;
        int n = n0 + wcol + j * 16 + l15;
        float v = alpha * acc[i][j][rg];
        if (addend) v += addend[(long)m * ldc + n];
        if (OBF) ((ushort_t*)C)[(long)m * ldc + n] = f2us(v);
        else     ((float*)C)[(long)m * ldc + n] = v;
      }
    }
  }
}

// ---------------- GEMM + fused GLU/SwiGLU epilogue (BM=64, BN=128 over a-cols) ----------------
// W is [2*NH][K]: a-rows at n, gate-rows at NH+n. Output [M][NH] bf16:
// SWI=false: a*sigmoid(g) (conv GLU); SWI=true: silu(a)*g (ffn SwiGLU).
template<bool SWI>
__global__ __launch_bounds__(256) void k_gemm_glu(const ushort_t* __restrict__ A,
    const ushort_t* __restrict__ W, ushort_t* __restrict__ C, int NH, int K) {
  __shared__ ushort_t As[64 * 64];
  __shared__ ushort_t Ws[256 * 64];
  int t = threadIdx.x;
  int m0 = blockIdx.y * 64, n0 = blockIdx.x * 128;
  int lane = t & 63, wv = t >> 6;
  int l15 = lane & 15, quad = lane >> 4;
  int wcol = wv * 32;
  floatx4 accA[4][2], accG[4][2];
#pragma unroll
  for (int i = 0; i < 4; ++i)
#pragma unroll
    for (int j = 0; j < 2; ++j) { accA[i][j] = 0; accG[i][j] = 0; }
  uint4 ra[2], rw[8];
#pragma unroll
  for (int i = 0; i < 2; ++i) { int idx = t + i * 256; int r = idx >> 3, c = idx & 7;
    ra[i] = *(const uint4*)(A + (long)(m0 + r) * K + c * 8); }
#pragma unroll
  for (int i = 0; i < 8; ++i) { int idx = t + i * 256; int r = idx >> 3, c = idx & 7;
    int grow = (r < 128) ? (n0 + r) : (NH + n0 + (r - 128));
    rw[i] = *(const uint4*)(W + (long)grow * K + c * 8); }
  for (int k0 = 0; k0 < K; k0 += 64) {
#pragma unroll
    for (int i = 0; i < 2; ++i) { int idx = t + i * 256; int r = idx >> 3, c = idx & 7;
      *(uint4*)&As[r * 64 + ((c ^ (r & 7)) << 3)] = ra[i]; }
#pragma unroll
    for (int i = 0; i < 8; ++i) { int idx = t + i * 256; int r = idx >> 3, c = idx & 7;
      *(uint4*)&Ws[r * 64 + ((c ^ (r & 7)) << 3)] = rw[i]; }
    __syncthreads();
    int kn = k0 + 64;
    if (kn < K) {
#pragma unroll
      for (int i = 0; i < 2; ++i) { int idx = t + i * 256; int r = idx >> 3, c = idx & 7;
        ra[i] = *(const uint4*)(A + (long)(m0 + r) * K + kn + c * 8); }
#pragma unroll
      for (int i = 0; i < 8; ++i) { int idx = t + i * 256; int r = idx >> 3, c = idx & 7;
        int grow = (r < 128) ? (n0 + r) : (NH + n0 + (r - 128));
        rw[i] = *(const uint4*)(W + (long)grow * K + kn + c * 8); }
    }
#pragma unroll
    for (int half = 0; half < 2; ++half) {
      int sw = ((half * 4 + quad) ^ (l15 & 7)) << 3;
      short8 af[4], ba[2], bg[2];
#pragma unroll
      for (int i = 0; i < 4; ++i) af[i] = *(short8*)&As[(i * 16 + l15) * 64 + sw];
#pragma unroll
      for (int j = 0; j < 2; ++j) {
        ba[j] = *(short8*)&Ws[(wcol + j * 16 + l15) * 64 + sw];
        bg[j] = *(short8*)&Ws[(128 + wcol + j * 16 + l15) * 64 + sw];
      }
#pragma unroll
      for (int i = 0; i < 4; ++i)
#pragma unroll
        for (int j = 0; j < 2; ++j) {
          accA[i][j] = __builtin_amdgcn_mfma_f32_16x16x32_bf16(af[i], ba[j], accA[i][j], 0, 0, 0);
          accG[i][j] = __builtin_amdgcn_mfma_f32_16x16x32_bf16(af[i], bg[j], accG[i][j], 0, 0, 0);
        }
    }
    __syncthreads();
  }
#pragma unroll
  for (int i = 0; i < 4; ++i) {
#pragma unroll
    for (int j = 0; j < 2; ++j) {
#pragma unroll
      for (int rg = 0; rg < 4; ++rg) {
        int m = m0 + i * 16 + quad * 4 + rg;
        int n = n0 + wcol + j * 16 + l15;
        float a = accA[i][j][rg], g = accG[i][j][rg];
        float o = SWI ? (a / (1.0f + __expf(-a))) * g
                      : a * (1.0f / (1.0f + __expf(-g)));
        C[(long)m * NH + n] = f2us(o);
      }
    }
  }
}

// ---------------- Rq GEMM (bf16): Rq[(bh*1024+qo)][ri] = q . rel[min(ri,382)] ----------------
__global__ __launch_bounds__(256) void k_rq_b(const ushort_t* __restrict__ qkv,
    const ushort_t* __restrict__ relB, bf16* __restrict__ Rq) {
  __shared__ ushort_t As[128 * 64];
  __shared__ ushort_t Ws[128 * 64];
  int t = threadIdx.x;
  int bh = blockIdx.z;
  const ushort_t* A = qkv + (long)(bh >> 3) * Tc * 768 + (bh & 7) * 64;
  int m0 = blockIdx.y * 128, n0 = blockIdx.x * 128;
  int lane = t & 63, wv = t >> 6;
  int l15 = lane & 15, quad = lane >> 4;
  int wrow = (wv >> 1) * 64, wcol = (wv & 1) * 64;
  floatx4 acc[4][4];
#pragma unroll
  for (int i = 0; i < 4; ++i)
#pragma unroll
    for (int j = 0; j < 4; ++j) acc[i][j] = 0;
#pragma unroll
  for (int i = t; i < 128 * 8; i += 256) {
    int r = i >> 3, c = i & 7;
    uint4 v = *(const uint4*)(A + (long)(m0 + r) * 768 + c * 8);
    *(uint4*)&As[r * 64 + ((c ^ (r & 7)) << 3)] = v;
  }
#pragma unroll
  for (int i = t; i < 128 * 8; i += 256) {
    int r = i >> 3, c = i & 7;
    int wr = n0 + r; if (wr > 382) wr = 382;
    uint4 v = *(const uint4*)(relB + (long)wr * 64 + c * 8);
    *(uint4*)&Ws[r * 64 + ((c ^ (r & 7)) << 3)] = v;
  }
  __syncthreads();
#pragma unroll
  for (int half = 0; half < 2; ++half) {
    int sw = ((half * 4 + quad) ^ (l15 & 7)) << 3;
    short8 af[4], bfr[4];
#pragma unroll
    for (int i = 0; i < 4; ++i) af[i] = *(short8*)&As[(wrow + i * 16 + l15) * 64 + sw];
#pragma unroll
    for (int j = 0; j < 4; ++j) bfr[j] = *(short8*)&Ws[(wcol + j * 16 + l15) * 64 + sw];
#pragma unroll
    for (int i = 0; i < 4; ++i)
#pragma unroll
      for (int j = 0; j < 4; ++j)
        acc[i][j] = __builtin_amdgcn_mfma_f32_16x16x32_bf16(af[i], bfr[j], acc[i][j], 0, 0, 0);
  }
#pragma unroll
  for (int i = 0; i < 4; ++i)
#pragma unroll
    for (int j = 0; j < 4; ++j)
#pragma unroll
      for (int rg = 0; rg < 4; ++rg) {
        int m = m0 + wrow + i * 16 + quad * 4 + rg;
        int n = n0 + wcol + j * 16 + l15;
        Rq[((long)bh * Tc + m) * 384 + n] = __float2bfloat16(acc[i][j][rg]);
      }
}

// ---------------- MFMA flash attention (qkv fused buffer, stride 768) ----------------
template<bool INV>
__global__ __launch_bounds__(256) void k_attn_flash(const ushort_t* __restrict__ qkv,
    const bf16* __restrict__ Rq, const int* __restrict__ alen, ushort_t* __restrict__ out) {
  int qt = blockIdx.x, h = blockIdx.y, b = blockIdx.z;
  int len = alen[b];
  int q0 = qt * 64;
  if (INV) { if (q0 + 64 <= len) return; }
  else     { if (q0 >= len) return; }
  int nskip = max(len - q0, 0);
  int nvalid = min(len - q0, 64);
  int g = h >> 2;
  __shared__ __align__(16) ushort_t Qs[64 * 72];
  __shared__ __align__(16) ushort_t Ks[64 * 72];
  __shared__ __align__(16) ushort_t Vt[64 * 72];
  __shared__ __align__(16) ushort_t Ps[64 * 72];
  int t = threadIdx.x;
  int lane = t & 63, w = t >> 6;
  int l15 = lane & 15, quad = lane >> 4;
  int qw = w * 16;
  {
    int qi = t >> 2, du = (t & 3) * 16;
    const ushort_t* src = qkv + ((long)(b * Tc + q0 + qi)) * 768 + h * 64 + du;
    *(uint4*)&Qs[qi * 72 + du] = *(const uint4*)(src);
    *(uint4*)&Qs[qi * 72 + du + 8] = *(const uint4*)(src + 8);
  }
  float m_[4], l_[4], alpha[4];
  floatx4 acc[4];
#pragma unroll
  for (int r = 0; r < 4; ++r) { m_[r] = NEGB; l_[r] = 0.f; acc[r] = 0; }
  const ushort_t* Rqu = (const ushort_t*)Rq;
  long rqrow = (long)(b * 8 + h) * Tc + q0;
  float rqlo[4], rqhi[4];
  if (INV) {
#pragma unroll
    for (int r = 0; r < 4; ++r) {
      long ri = (rqrow + qw + quad * 4 + r) * 384;
      rqlo[r] = us2f(Rqu[ri]);          // dist clamped to -191
      rqhi[r] = us2f(Rqu[ri + 382]);    // dist clamped to +191
    }
  }
  const int NT = INV ? 18 : 3;
  for (int kt = 0; kt < NT; ++kt) {
    int ko0 = INV ? (kt * 64 - 128) : (q0 - 128 + kt * 64);
    __syncthreads();
    {
      int kj = t >> 2, du = (t & 3) * 16;
      int ko = ko0 + kj;
      if (ko >= 0) {
        long base = ((long)(b * Tc + ko)) * 768 + 512 + g * 64 + du;
        *(uint4*)&Ks[kj * 72 + du] = *(const uint4*)(qkv + base);
        *(uint4*)&Ks[kj * 72 + du + 8] = *(const uint4*)(qkv + base + 8);
        const ushort_t* vs = qkv + base + 128;
#pragma unroll
        for (int u = 0; u < 16; ++u) Vt[(du + u) * 72 + kj] = vs[u];
      } else {
        uint4 z = {0, 0, 0, 0};
        *(uint4*)&Ks[kj * 72 + du] = z;
        *(uint4*)&Ks[kj * 72 + du + 8] = z;
#pragma unroll
        for (int u = 0; u < 16; ++u) Vt[(du + u) * 72 + kj] = 0;
      }
    }
    __syncthreads();
    short8 aq0 = *(short8*)&Qs[(qw + l15) * 72 + quad * 8];
    short8 aq1 = *(short8*)&Qs[(qw + l15) * 72 + 32 + quad * 8];
    floatx4 s[4];
#pragma unroll
    for (int nt = 0; nt < 4; ++nt) {
      short8 bk0 = *(short8*)&Ks[(nt * 16 + l15) * 72 + quad * 8];
      short8 bk1 = *(short8*)&Ks[(nt * 16 + l15) * 72 + 32 + quad * 8];
      floatx4 z = {0.f, 0.f, 0.f, 0.f};
      z = __builtin_amdgcn_mfma_f32_16x16x32_bf16(aq0, bk0, z, 0, 0, 0);
      z = __builtin_amdgcn_mfma_f32_16x16x32_bf16(aq1, bk1, z, 0, 0, 0);
      s[nt] = z;
    }
#pragma unroll
    for (int nt = 0; nt < 4; ++nt) {
      int ko = ko0 + nt * 16 + l15;
      bool msk = (!INV) && (ko >= len);
#pragma unroll
      for (int r = 0; r < 4; ++r) {
        int qi = qw + quad * 4 + r;
        int dist = (q0 + qi) - ko;
        float rv;
        if (INV && dist <= -(MPc - 1)) rv = rqlo[r];
        else if (INV && dist >= (MPc - 1)) rv = rqhi[r];
        else {
          int dd = min(max(dist, -(MPc - 1)), MPc - 1);
          rv = us2f(Rqu[(rqrow + qi) * 384 + dd + 191]);
        }
        s[nt][r] = msk ? NEGB : (s[nt][r] + rv);
      }
    }
#pragma unroll
    for (int r = 0; r < 4; ++r) {
      float mx = fmaxf(fmaxf(s[0][r], s[1][r]), fmaxf(s[2][r], s[3][r]));
#pragma unroll
      for (int o = 1; o < 16; o <<= 1) mx = fmaxf(mx, __shfl_xor(mx, o, 64));
      float mn = fmaxf(m_[r], mx);
      alpha[r] = __expf(m_[r] - mn);
      float p0 = __expf(s[0][r] - mn), p1 = __expf(s[1][r] - mn);
      float p2 = __expf(s[2][r] - mn), p3 = __expf(s[3][r] - mn);
      s[0][r] = p0; s[1][r] = p1; s[2][r] = p2; s[3][r] = p3;
      float ps = p0 + p1 + p2 + p3;
#pragma unroll
      for (int o = 1; o < 16; o <<= 1) ps += __shfl_xor(ps, o, 64);
      l_[r] = l_[r] * alpha[r] + ps;
      m_[r] = mn;
    }
#pragma unroll
    for (int nt = 0; nt < 4; ++nt)
#pragma unroll
      for (int r = 0; r < 4; ++r)
        Ps[(qw + quad * 4 + r) * 72 + nt * 16 + l15] = f2us(s[nt][r]);
#pragma unroll
    for (int j = 0; j < 4; ++j)
#pragma unroll
      for (int r = 0; r < 4; ++r) acc[j][r] *= alpha[r];
    short8 ap0 = *(short8*)&Ps[(qw + l15) * 72 + quad * 8];
    short8 ap1 = *(short8*)&Ps[(qw + l15) * 72 + 32 + quad * 8];
#pragma unroll
    for (int j = 0; j < 4; ++j) {
      short8 bv0 = *(short8*)&Vt[(j * 16 + l15) * 72 + quad * 8];
      short8 bv1 = *(short8*)&Vt[(j * 16 + l15) * 72 + 32 + quad * 8];
      acc[j] = __builtin_amdgcn_mfma_f32_16x16x32_bf16(ap0, bv0, acc[j], 0, 0, 0);
      acc[j] = __builtin_amdgcn_mfma_f32_16x16x32_bf16(ap1, bv1, acc[j], 0, 0, 0);
    }
  }
#pragma unroll
  for (int r = 0; r < 4; ++r) {
    int qi = qw + quad * 4 + r;
    bool wr = INV ? (qi >= nskip) : (qi < nvalid);
    if (wr) {
      float inv = 1.0f / l_[r];
#pragma unroll
      for (int j = 0; j < 4; ++j)
        out[((long)(b * Tc + q0 + qi)) * Dc + h * 64 + j * 16 + l15] = f2us(acc[j][r] * inv);
    }
  }
}

// ---------------- depthwise conv(9, pad4) + silu: in [NBT][512] bf16 ----------------
__global__ void k_dwconv(const ushort_t* __restrict__ in, const ushort_t* __restrict__ dw,
                         ushort_t* __restrict__ out, int n) {
  int i = blockIdx.x * 256 + threadIdx.x;
  if (i >= n) return;
  int d = i & 511;
  int t = (i >> 9) & (Tc - 1);
  int b = i >> 19;
  float acc = 0.0f;
#pragma unroll
  for (int j = 0; j < 9; ++j) {
    int tt = t + j - 4;
    if (tt >= 0 && tt < Tc) acc += us2f(in[((long)(b * Tc + tt)) * 512 + d]) * us2f(dw[d * 9 + j]);
  }
  out[i] = f2us(acc * (1.0f / (1.0f + __expf(-acc))));
}

extern "C" void kernel_launch(void* const* d_in, const int* in_sizes, int n_in,
                              void* d_out, int out_size, void* d_ws, size_t ws_size,
                              hipStream_t stream) {
  const void* x_in = d_in[0];
  const int*  alen = (const int*)d_in[1];
  const void* ln1w = d_in[2];
  const void* ln1b = d_in[3];
  const void* wq   = d_in[4];
  const void* wk   = d_in[5];
  const void* wv   = d_in[6];
  const void* wo   = d_in[7];
  const void* rel  = d_in[8];
  const void* ln2w = d_in[9];
  const void* ln2b = d_in[10];
  const void* pw1  = d_in[11];
  const void* dwv  = d_in[12];
  const void* pw2  = d_in[13];
  const void* ln3w = d_in[14];
  const void* ln3b = d_in[15];
  const void* w1   = d_in[16];
  const void* w2   = d_in[17];

  // ---- workspace layout (bytes) ----
  char* base = (char*)d_ws;
  int*      flag = (int*)base;                       // 256
  float*    xf   = (float*)(base + 256);             // 8 MB f32 residual
  float*    lnb  = (float*)(base + 256 + 8388608);   // 8 MB f32 LN out (addend)
  ushort_t* lnA  = (ushort_t*)(base + 16777472);     // 4 MB bf16 LN out (GEMM A)
  ushort_t* wbf  = (ushort_t*)(base + 20971776);     // 24,350,208 B bf16 weights
  char*     U    = base + 45321984;                  // phase union
  // attn phase
  ushort_t* qkv = (ushort_t*)U;                      // [NBT][768] = 6 MB
  ushort_t* ab  = (ushort_t*)(U + 6291456);          // 4 MB
  bf16*     Rq  = (bf16*)(U + 10485760);             // 25,165,824 B
  // conv phase
  ushort_t* gl = (ushort_t*)U;                       // [NBT][512] 4 MB
  ushort_t* cb = (ushort_t*)(U + 4194304);           // 4 MB
  // ffn phase: sw = U, [NBT][1024] 8 MB
  ushort_t* sw = (ushort_t*)U;
  size_t REQ = 45321984 + 35651584;
  if (ws_size < REQ) return;

  // bf16 weight table offsets (elements)
  ushort_t* wqkvB = wbf + 0;            // [L][768][512], Wq pre-scaled 0.125
  ushort_t* woB   = wbf + 1572864;
  ushort_t* relB  = wbf + 2621440;
  ushort_t* pw1B  = wbf + 2719488;
  ushort_t* dwB   = wbf + 4816640;
  ushort_t* pw2B  = wbf + 4835072;
  ushort_t* w1B   = wbf + 5883648;
  ushort_t* w2B   = wbf + 10077952;

  k_detect<<<1, 256, 0, stream>>>(x_in, flag);
  k_in<<<(int)((NE + 255) / 256), 256, 0, stream>>>(x_in, xf, (int)NE, flag);
  for (int l = 0; l < 4; ++l) {
    k_w2b<<<1024, 256, 0, stream>>>(wq, (long)l * 262144, wqkvB + (long)l * 393216, 262144, 0.125f, flag);
    k_w2b<<<256,  256, 0, stream>>>(wk, (long)l * 65536, wqkvB + (long)l * 393216 + 262144, 65536, 1.0f, flag);
    k_w2b<<<256,  256, 0, stream>>>(wv, (long)l * 65536, wqkvB + (long)l * 393216 + 327680, 65536, 1.0f, flag);
  }
  k_w2b<<<4096, 256, 0, stream>>>(wo,  0, woB,  1048576, 1.0f, flag);
  k_w2b<<<383,  256, 0, stream>>>(rel, 0, relB, 98048, 1.0f, flag);
  k_w2b<<<8192, 256, 0, stream>>>(pw1, 0, pw1B, 2097152, 1.0f, flag);
  k_w2b<<<72,   256, 0, stream>>>(dwv, 0, dwB,  18432, 1.0f, flag);
  k_w2b<<<4096, 256, 0, stream>>>(pw2, 0, pw2B, 1048576, 1.0f, flag);
  k_w2b<<<16384,256, 0, stream>>>(w1,  0, w1B,  4194304, 1.0f, flag);
  k_w2b<<<8192, 256, 0, stream>>>(w2,  0, w2B,  2097152, 1.0f, flag);

  for (int i = 0; i < 4; ++i) {
    long oLN = (long)i * Dc;
    // ---- attention ----
    k_ln<<<NBT, 256, 0, stream>>>(xf, ln1w, ln1b, oLN, lnb, lnA, flag);
    k_gemm_b<64, 128, true><<<dim3(6, 64), 256, 0, stream>>>(lnA, Dc, wqkvB + (long)i * 393216, qkv, 768, nullptr, 1.0f, 512);
    k_rq_b<<<dim3(3, 8, 32), 256, 0, stream>>>(qkv, relB + (long)i * 24512, Rq);
    k_attn_flash<false><<<dim3(16, 8, 4), 256, 0, stream>>>(qkv, Rq, alen, ab);
    k_attn_flash<true><<<dim3(16, 8, 4), 256, 0, stream>>>(qkv, Rq, alen, ab);
    k_gemm_b<64, 128, false><<<dim3(4, 64), 256, 0, stream>>>(ab, Dc, woB + (long)i * 262144, xf, Dc, lnb, 1.0f, 512);

    // ---- conv ----
    k_ln<<<NBT, 256, 0, stream>>>(xf, ln2w, ln2b, oLN, lnb, lnA, flag);
    k_gemm_glu<false><<<dim3(4, 64), 256, 0, stream>>>(lnA, pw1B + (long)i * 524288, gl, 512, 512);
    k_dwconv<<<NBT * 512 / 256, 256, 0, stream>>>(gl, dwB + (long)i * 4608, cb, NBT * 512);
    k_gemm_b<64, 128, false><<<dim3(4, 64), 256, 0, stream>>>(cb, Dc, pw2B + (long)i * 262144, xf, Dc, lnb, 1.0f, 512);

    // ---- ffn ----
    k_ln<<<NBT, 256, 0, stream>>>(xf, ln3w, ln3b, oLN, lnb, lnA, flag);
    k_gemm_glu<true><<<dim3(8, 64), 256, 0, stream>>>(lnA, w1B + (long)i * 1048576, sw, 1024, 512);
    k_gemm_b<64, 128, false><<<dim3(4, 64), 256, 0, stream>>>(sw, 1024, w2B + (long)i * 524288, xf, Dc, lnb, 1.0f, 1024);
  }

  k_out<<<(int)((NE + 255) / 256), 256, 0, stream>>>(xf, d_out, (int)NE, flag);
}

// Round 9
// 1493.185 us; speedup vs baseline: 1.0661x; 1.0661x over previous
//
#include <hip/hip_runtime.h>
#include <hip/hip_bf16.h>

typedef __hip_bfloat16 bf16;
typedef unsigned short ushort_t;
typedef unsigned int uint_t;
typedef __attribute__((ext_vector_type(8))) short short8;
typedef __attribute__((ext_vector_type(4))) float floatx4;

__device__ __forceinline__ float b2f(bf16 x) { return __bfloat162float(x); }
__device__ __forceinline__ ushort_t f2us(float f) { bf16 h = __float2bfloat16(f); return *(ushort_t*)&h; }
__device__ __forceinline__ float us2f(ushort_t u) { return __uint_as_float(((uint_t)u) << 16); }

constexpr int Bc = 4, Tc = 1024, Dc = 512, Hc = 8, HDc = 64;
constexpr int LCc = 128, MPc = 192;
constexpr float EPSc = 1e-4f;
constexpr int NBT = Bc * Tc;
constexpr long NE = (long)NBT * Dc;
constexpr float NEGB = -1e30f;

__device__ __forceinline__ float wload(const void* p, long i, int f32) {
  return f32 ? ((const float*)p)[i] : b2f(((const bf16*)p)[i]);
}

// ---------------- dtype detector ----------------
__global__ void k_detect(const void* __restrict__ x, int* __restrict__ flag) {
  __shared__ int s[256];
  int t = threadIdx.x;
  const unsigned short* u = (const unsigned short*)x;
  int bad = 0;
  for (int j = t; j < 2048; j += 256) {
    int e = (u[j] >> 7) & 0xFF;
    if (e == 0xFF || e > 0x8F || (e != 0 && e < 0x6F)) bad++;
  }
  s[t] = bad;
  __syncthreads();
  for (int off = 128; off > 0; off >>= 1) { if (t < off) s[t] += s[t + off]; __syncthreads(); }
  if (t == 0) flag[0] = (s[0] > 16) ? 1 : 0;
}

__global__ void k_in(const void* __restrict__ in, float* __restrict__ out, int n,
                     const int* __restrict__ flag) {
  int i = blockIdx.x * 256 + threadIdx.x;
  if (i < n) out[i] = wload(in, i, flag[0]);
}
__global__ void k_out(const float* __restrict__ in, void* __restrict__ out, int n,
                      const int* __restrict__ flag) {
  int i = blockIdx.x * 256 + threadIdx.x;
  if (i >= n) return;
  if (flag[0]) ((float*)out)[i] = in[i];
  else         ((bf16*)out)[i] = __float2bfloat16(in[i]);
}
__global__ void k_w2b(const void* __restrict__ src, long srcoff, ushort_t* __restrict__ dst,
                      int n, float scale, const int* __restrict__ flag) {
  int i = blockIdx.x * 256 + threadIdx.x;
  if (i < n) dst[i] = f2us(wload(src, srcoff + i, flag[0]) * scale);
}

// ---------------- LayerNorm: writes f32 (residual addend) + bf16 (GEMM A) ----------------
__global__ __launch_bounds__(256) void k_ln(const float* __restrict__ x,
    const void* __restrict__ w, const void* __restrict__ bb, long woff,
    float* __restrict__ o, ushort_t* __restrict__ oA, const int* __restrict__ flag) {
  int f32 = flag[0];
  int row = blockIdx.x;
  int t = threadIdx.x;
  const float* xr = x + (long)row * Dc;
  float x0 = xr[t], x1 = xr[t + 256];
  __shared__ float red[256];
  red[t] = x0 + x1;
  __syncthreads();
  for (int off = 128; off > 0; off >>= 1) { if (t < off) red[t] += red[t + off]; __syncthreads(); }
  float mean = red[0] * (1.0f / Dc);
  __syncthreads();
  float d0 = x0 - mean, d1 = x1 - mean;
  red[t] = d0 * d0 + d1 * d1;
  __syncthreads();
  for (int off = 128; off > 0; off >>= 1) { if (t < off) red[t] += red[t + off]; __syncthreads(); }
  float inv = 1.0f / sqrtf(red[0] * (1.0f / Dc) + EPSc);
  float v0 = d0 * inv * wload(w, woff + t, f32)       + wload(bb, woff + t, f32);
  float v1 = d1 * inv * wload(w, woff + t + 256, f32) + wload(bb, woff + t + 256, f32);
  float* orow = o + (long)row * Dc;
  ushort_t* arow = oA + (long)row * Dc;
  orow[t] = v0; orow[t + 256] = v1;
  arow[t] = f2us(v0); arow[t + 256] = f2us(v1);
}

// ---------------- bf16 MFMA GEMM with register-prefetch pipeline ----------------
template<int BM, int BN, bool OBF>
__global__ __launch_bounds__(256) void k_gemm_b(const ushort_t* __restrict__ A, int lda,
    const ushort_t* __restrict__ W, void* __restrict__ C, int ldc,
    const float* __restrict__ addend, float alpha, int K) {
  constexpr int WGM = BM / 64;
  constexpr int WGN = 4 / WGM;
  constexpr int WN = BN / WGN;
  constexpr int NJ = WN / 16;
  constexpr int NA = BM * 8 / 256;
  constexpr int NW = BN * 8 / 256;
  __shared__ ushort_t As[BM * 64];
  __shared__ ushort_t Ws[BN * 64];
  int t = threadIdx.x;
  int m0 = blockIdx.y * BM, n0 = blockIdx.x * BN;
  int lane = t & 63, wv = t >> 6;
  int l15 = lane & 15, quad = lane >> 4;
  int wrow = (WGM == 2) ? (wv >> 1) * 64 : 0;
  int wcol = (WGM == 2) ? (wv & 1) * WN : wv * WN;
  floatx4 acc[4][NJ];
#pragma unroll
  for (int i = 0; i < 4; ++i)
#pragma unroll
    for (int j = 0; j < NJ; ++j) acc[i][j] = 0;
  uint4 ra[NA], rw[NW];
#pragma unroll
  for (int i = 0; i < NA; ++i) { int idx = t + i * 256; int r = idx >> 3, c = idx & 7;
    ra[i] = *(const uint4*)(A + (long)(m0 + r) * lda + c * 8); }
#pragma unroll
  for (int i = 0; i < NW; ++i) { int idx = t + i * 256; int r = idx >> 3, c = idx & 7;
    rw[i] = *(const uint4*)(W + (long)(n0 + r) * K + c * 8); }
  for (int k0 = 0; k0 < K; k0 += 64) {
#pragma unroll
    for (int i = 0; i < NA; ++i) { int idx = t + i * 256; int r = idx >> 3, c = idx & 7;
      *(uint4*)&As[r * 64 + ((c ^ (r & 7)) << 3)] = ra[i]; }
#pragma unroll
    for (int i = 0; i < NW; ++i) { int idx = t + i * 256; int r = idx >> 3, c = idx & 7;
      *(uint4*)&Ws[r * 64 + ((c ^ (r & 7)) << 3)] = rw[i]; }
    __syncthreads();
    int kn = k0 + 64;
    if (kn < K) {
#pragma unroll
      for (int i = 0; i < NA; ++i) { int idx = t + i * 256; int r = idx >> 3, c = idx & 7;
        ra[i] = *(const uint4*)(A + (long)(m0 + r) * lda + kn + c * 8); }
#pragma unroll
      for (int i = 0; i < NW; ++i) { int idx = t + i * 256; int r = idx >> 3, c = idx & 7;
        rw[i] = *(const uint4*)(W + (long)(n0 + r) * K + kn + c * 8); }
    }
#pragma unroll
    for (int half = 0; half < 2; ++half) {
      int sw = ((half * 4 + quad) ^ (l15 & 7)) << 3;
      short8 af[4], bfr[NJ];
#pragma unroll
      for (int i = 0; i < 4; ++i) af[i] = *(short8*)&As[(wrow + i * 16 + l15) * 64 + sw];
#pragma unroll
      for (int j = 0; j < NJ; ++j) bfr[j] = *(short8*)&Ws[(wcol + j * 16 + l15) * 64 + sw];
#pragma unroll
      for (int i = 0; i < 4; ++i)
#pragma unroll
        for (int j = 0; j < NJ; ++j)
          acc[i][j] = __builtin_amdgcn_mfma_f32_16x16x32_bf16(af[i], bfr[j], acc[i][j], 0, 0, 0);
    }
    __syncthreads();
  }
#pragma unroll
  for (int i = 0; i < 4; ++i) {
#pragma unroll
    for (int j = 0; j < NJ; ++j) {
#pragma unroll
      for (int rg = 0; rg < 4; ++rg) {
        int m = m0 + wrow + i * 16 + quad * 4 + rg;
        int n = n0 + wcol + j * 16 + l15;
        float v = alpha * acc[i][j][rg];
        if (addend) v += addend[(long)m * ldc + n];
        if (OBF) ((ushort_t*)C)[(long)m * ldc + n] = f2us(v);
        else     ((float*)C)[(long)m * ldc + n] = v;
      }
    }
  }
}

// ---------------- fused QKV GEMM: W [768][512] (q rows pre-scaled); epilogue splits ----------------
// block n0: 0..3 -> qb (ldc 512), 4 -> kb (ldc 128), 5 -> vb (ldc 128). Block-uniform.
__global__ __launch_bounds__(256) void k_gemm_qkv(const ushort_t* __restrict__ A,
    const ushort_t* __restrict__ W, ushort_t* __restrict__ qb, ushort_t* __restrict__ kb,
    ushort_t* __restrict__ vb, int K) {
  __shared__ ushort_t As[64 * 64];
  __shared__ ushort_t Ws[128 * 64];
  int t = threadIdx.x;
  int m0 = blockIdx.y * 64, n0 = blockIdx.x * 128;
  int lane = t & 63, wv = t >> 6;
  int l15 = lane & 15, quad = lane >> 4;
  int wcol = wv * 32;
  floatx4 acc[4][2];
#pragma unroll
  for (int i = 0; i < 4; ++i)
#pragma unroll
    for (int j = 0; j < 2; ++j) acc[i][j] = 0;
  uint4 ra[2], rw[4];
#pragma unroll
  for (int i = 0; i < 2; ++i) { int idx = t + i * 256; int r = idx >> 3, c = idx & 7;
    ra[i] = *(const uint4*)(A + (long)(m0 + r) * K + c * 8); }
#pragma unroll
  for (int i = 0; i < 4; ++i) { int idx = t + i * 256; int r = idx >> 3, c = idx & 7;
    rw[i] = *(const uint4*)(W + (long)(n0 + r) * K + c * 8); }
  for (int k0 = 0; k0 < K; k0 += 64) {
#pragma unroll
    for (int i = 0; i < 2; ++i) { int idx = t + i * 256; int r = idx >> 3, c = idx & 7;
      *(uint4*)&As[r * 64 + ((c ^ (r & 7)) << 3)] = ra[i]; }
#pragma unroll
    for (int i = 0; i < 4; ++i) { int idx = t + i * 256; int r = idx >> 3, c = idx & 7;
      *(uint4*)&Ws[r * 64 + ((c ^ (r & 7)) << 3)] = rw[i]; }
    __syncthreads();
    int kn = k0 + 64;
    if (kn < K) {
#pragma unroll
      for (int i = 0; i < 2; ++i) { int idx = t + i * 256; int r = idx >> 3, c = idx & 7;
        ra[i] = *(const uint4*)(A + (long)(m0 + r) * K + kn + c * 8); }
#pragma unroll
      for (int i = 0; i < 4; ++i) { int idx = t + i * 256; int r = idx >> 3, c = idx & 7;
        rw[i] = *(const uint4*)(W + (long)(n0 + r) * K + kn + c * 8); }
    }
#pragma unroll
    for (int half = 0; half < 2; ++half) {
      int sw = ((half * 4 + quad) ^ (l15 & 7)) << 3;
      short8 af[4], bfr[2];
#pragma unroll
      for (int i = 0; i < 4; ++i) af[i] = *(short8*)&As[(i * 16 + l15) * 64 + sw];
#pragma unroll
      for (int j = 0; j < 2; ++j) bfr[j] = *(short8*)&Ws[(wcol + j * 16 + l15) * 64 + sw];
#pragma unroll
      for (int i = 0; i < 4; ++i)
#pragma unroll
        for (int j = 0; j < 2; ++j)
          acc[i][j] = __builtin_amdgcn_mfma_f32_16x16x32_bf16(af[i], bfr[j], acc[i][j], 0, 0, 0);
    }
    __syncthreads();
  }
  ushort_t* dst; int ldc2, nb;
  if (n0 < 512)      { dst = qb; ldc2 = 512; nb = n0; }
  else if (n0 == 512){ dst = kb; ldc2 = 128; nb = 0; }
  else               { dst = vb; ldc2 = 128; nb = 0; }
#pragma unroll
  for (int i = 0; i < 4; ++i)
#pragma unroll
    for (int j = 0; j < 2; ++j)
#pragma unroll
      for (int rg = 0; rg < 4; ++rg) {
        int m = m0 + i * 16 + quad * 4 + rg;
        int n = nb + wcol + j * 16 + l15;
        dst[(long)m * ldc2 + n] = f2us(acc[i][j][rg]);
      }
}

// ---------------- GEMM + fused GLU/SwiGLU epilogue ----------------
template<bool SWI>
__global__ __launch_bounds__(256) void k_gemm_glu(const ushort_t* __restrict__ A,
    const ushort_t* __restrict__ W, ushort_t* __restrict__ C, int NH, int K) {
  __shared__ ushort_t As[64 * 64];
  __shared__ ushort_t Ws[256 * 64];
  int t = threadIdx.x;
  int m0 = blockIdx.y * 64, n0 = blockIdx.x * 128;
  int lane = t & 63, wv = t >> 6;
  int l15 = lane & 15, quad = lane >> 4;
  int wcol = wv * 32;
  floatx4 accA[4][2], accG[4][2];
#pragma unroll
  for (int i = 0; i < 4; ++i)
#pragma unroll
    for (int j = 0; j < 2; ++j) { accA[i][j] = 0; accG[i][j] = 0; }
  uint4 ra[2], rw[8];
#pragma unroll
  for (int i = 0; i < 2; ++i) { int idx = t + i * 256; int r = idx >> 3, c = idx & 7;
    ra[i] = *(const uint4*)(A + (long)(m0 + r) * K + c * 8); }
#pragma unroll
  for (int i = 0; i < 8; ++i) { int idx = t + i * 256; int r = idx >> 3, c = idx & 7;
    int grow = (r < 128) ? (n0 + r) : (NH + n0 + (r - 128));
    rw[i] = *(const uint4*)(W + (long)grow * K + c * 8); }
  for (int k0 = 0; k0 < K; k0 += 64) {
#pragma unroll
    for (int i = 0; i < 2; ++i) { int idx = t + i * 256; int r = idx >> 3, c = idx & 7;
      *(uint4*)&As[r * 64 + ((c ^ (r & 7)) << 3)] = ra[i]; }
#pragma unroll
    for (int i = 0; i < 8; ++i) { int idx = t + i * 256; int r = idx >> 3, c = idx & 7;
      *(uint4*)&Ws[r * 64 + ((c ^ (r & 7)) << 3)] = rw[i]; }
    __syncthreads();
    int kn = k0 + 64;
    if (kn < K) {
#pragma unroll
      for (int i = 0; i < 2; ++i) { int idx = t + i * 256; int r = idx >> 3, c = idx & 7;
        ra[i] = *(const uint4*)(A + (long)(m0 + r) * K + kn + c * 8); }
#pragma unroll
      for (int i = 0; i < 8; ++i) { int idx = t + i * 256; int r = idx >> 3, c = idx & 7;
        int grow = (r < 128) ? (n0 + r) : (NH + n0 + (r - 128));
        rw[i] = *(const uint4*)(W + (long)grow * K + kn + c * 8); }
    }
#pragma unroll
    for (int half = 0; half < 2; ++half) {
      int sw = ((half * 4 + quad) ^ (l15 & 7)) << 3;
      short8 af[4], ba[2], bg[2];
#pragma unroll
      for (int i = 0; i < 4; ++i) af[i] = *(short8*)&As[(i * 16 + l15) * 64 + sw];
#pragma unroll
      for (int j = 0; j < 2; ++j) {
        ba[j] = *(short8*)&Ws[(wcol + j * 16 + l15) * 64 + sw];
        bg[j] = *(short8*)&Ws[(128 + wcol + j * 16 + l15) * 64 + sw];
      }
#pragma unroll
      for (int i = 0; i < 4; ++i)
#pragma unroll
        for (int j = 0; j < 2; ++j) {
          accA[i][j] = __builtin_amdgcn_mfma_f32_16x16x32_bf16(af[i], ba[j], accA[i][j], 0, 0, 0);
          accG[i][j] = __builtin_amdgcn_mfma_f32_16x16x32_bf16(af[i], bg[j], accG[i][j], 0, 0, 0);
        }
    }
    __syncthreads();
  }
#pragma unroll
  for (int i = 0; i < 4; ++i) {
#pragma unroll
    for (int j = 0; j < 2; ++j) {
#pragma unroll
      for (int rg = 0; rg < 4; ++rg) {
        int m = m0 + i * 16 + quad * 4 + rg;
        int n = n0 + wcol + j * 16 + l15;
        float a = accA[i][j][rg], g = accG[i][j][rg];
        float o = SWI ? (a / (1.0f + __expf(-a))) * g
                      : a * (1.0f / (1.0f + __expf(-g)));
        C[(long)m * NH + n] = f2us(o);
      }
    }
  }
}

// ---------------- Rq GEMM (bf16, qb stride 512) ----------------
__global__ __launch_bounds__(256) void k_rq_b(const ushort_t* __restrict__ qb,
    const ushort_t* __restrict__ relB, bf16* __restrict__ Rq) {
  __shared__ ushort_t As[128 * 64];
  __shared__ ushort_t Ws[128 * 64];
  int t = threadIdx.x;
  int bh = blockIdx.z;
  const ushort_t* A = qb + (long)(bh >> 3) * Tc * Dc + (bh & 7) * 64;
  int m0 = blockIdx.y * 128, n0 = blockIdx.x * 128;
  int lane = t & 63, wv = t >> 6;
  int l15 = lane & 15, quad = lane >> 4;
  int wrow = (wv >> 1) * 64, wcol = (wv & 1) * 64;
  floatx4 acc[4][4];
#pragma unroll
  for (int i = 0; i < 4; ++i)
#pragma unroll
    for (int j = 0; j < 4; ++j) acc[i][j] = 0;
#pragma unroll
  for (int i = t; i < 128 * 8; i += 256) {
    int r = i >> 3, c = i & 7;
    uint4 v = *(const uint4*)(A + (long)(m0 + r) * Dc + c * 8);
    *(uint4*)&As[r * 64 + ((c ^ (r & 7)) << 3)] = v;
  }
#pragma unroll
  for (int i = t; i < 128 * 8; i += 256) {
    int r = i >> 3, c = i & 7;
    int wr = n0 + r; if (wr > 382) wr = 382;
    uint4 v = *(const uint4*)(relB + (long)wr * 64 + c * 8);
    *(uint4*)&Ws[r * 64 + ((c ^ (r & 7)) << 3)] = v;
  }
  __syncthreads();
#pragma unroll
  for (int half = 0; half < 2; ++half) {
    int sw = ((half * 4 + quad) ^ (l15 & 7)) << 3;
    short8 af[4], bfr[4];
#pragma unroll
    for (int i = 0; i < 4; ++i) af[i] = *(short8*)&As[(wrow + i * 16 + l15) * 64 + sw];
#pragma unroll
    for (int j = 0; j < 4; ++j) bfr[j] = *(short8*)&Ws[(wcol + j * 16 + l15) * 64 + sw];
#pragma unroll
    for (int i = 0; i < 4; ++i)
#pragma unroll
      for (int j = 0; j < 4; ++j)
        acc[i][j] = __builtin_amdgcn_mfma_f32_16x16x32_bf16(af[i], bfr[j], acc[i][j], 0, 0, 0);
  }
#pragma unroll
  for (int i = 0; i < 4; ++i)
#pragma unroll
    for (int j = 0; j < 4; ++j)
#pragma unroll
      for (int rg = 0; rg < 4; ++rg) {
        int m = m0 + wrow + i * 16 + quad * 4 + rg;
        int n = n0 + wcol + j * 16 + l15;
        Rq[((long)bh * Tc + m) * 384 + n] = __float2bfloat16(acc[i][j][rg]);
      }
}

// ---------------- MFMA flash attention (R7 form: compact kb/vb stride 128) ----------------
template<bool INV>
__global__ __launch_bounds__(256) void k_attn_flash(const ushort_t* __restrict__ q,
    const ushort_t* __restrict__ kb, const ushort_t* __restrict__ vb,
    const bf16* __restrict__ Rq, const int* __restrict__ alen, ushort_t* __restrict__ out) {
  int qt = blockIdx.x, h = blockIdx.y, b = blockIdx.z;
  int len = alen[b];
  int q0 = qt * 64;
  if (INV) { if (q0 + 64 <= len) return; }
  else     { if (q0 >= len) return; }
  int nskip = max(len - q0, 0);
  int nvalid = min(len - q0, 64);
  int g = h >> 2;
  __shared__ __align__(16) ushort_t Qs[64 * 72];
  __shared__ __align__(16) ushort_t Ks[64 * 72];
  __shared__ __align__(16) ushort_t Vt[64 * 72];
  __shared__ __align__(16) ushort_t Ps[64 * 72];
  int t = threadIdx.x;
  int lane = t & 63, w = t >> 6;
  int l15 = lane & 15, quad = lane >> 4;
  int qw = w * 16;
  {
    int qi = t >> 2, du = (t & 3) * 16;
    const ushort_t* src = q + ((long)(b * Tc + q0 + qi)) * Dc + h * 64 + du;
    *(uint4*)&Qs[qi * 72 + du] = *(const uint4*)(src);
    *(uint4*)&Qs[qi * 72 + du + 8] = *(const uint4*)(src + 8);
  }
  float m_[4], l_[4], alpha[4];
  floatx4 acc[4];
#pragma unroll
  for (int r = 0; r < 4; ++r) { m_[r] = NEGB; l_[r] = 0.f; acc[r] = 0; }
  const ushort_t* Rqu = (const ushort_t*)Rq;
  long rqrow = (long)(b * 8 + h) * Tc + q0;
  const int NT = INV ? 18 : 3;
  for (int kt = 0; kt < NT; ++kt) {
    int ko0 = INV ? (kt * 64 - 128) : (q0 - 128 + kt * 64);
    __syncthreads();
    {
      int kj = t >> 2, du = (t & 3) * 16;
      int ko = ko0 + kj;
      if (ko >= 0) {
        long base = ((long)(b * Tc + ko)) * 128 + g * 64 + du;
        *(uint4*)&Ks[kj * 72 + du] = *(const uint4*)(kb + base);
        *(uint4*)&Ks[kj * 72 + du + 8] = *(const uint4*)(kb + base + 8);
        const ushort_t* vs = vb + base;
#pragma unroll
        for (int u = 0; u < 16; ++u) Vt[(du + u) * 72 + kj] = vs[u];
      } else {
        uint4 z = {0, 0, 0, 0};
        *(uint4*)&Ks[kj * 72 + du] = z;
        *(uint4*)&Ks[kj * 72 + du + 8] = z;
#pragma unroll
        for (int u = 0; u < 16; ++u) Vt[(du + u) * 72 + kj] = 0;
      }
    }
    __syncthreads();
    short8 aq0 = *(short8*)&Qs[(qw + l15) * 72 + quad * 8];
    short8 aq1 = *(short8*)&Qs[(qw + l15) * 72 + 32 + quad * 8];
    floatx4 s[4];
#pragma unroll
    for (int nt = 0; nt < 4; ++nt) {
      short8 bk0 = *(short8*)&Ks[(nt * 16 + l15) * 72 + quad * 8];
      short8 bk1 = *(short8*)&Ks[(nt * 16 + l15) * 72 + 32 + quad * 8];
      floatx4 z = {0.f, 0.f, 0.f, 0.f};
      z = __builtin_amdgcn_mfma_f32_16x16x32_bf16(aq0, bk0, z, 0, 0, 0);
      z = __builtin_amdgcn_mfma_f32_16x16x32_bf16(aq1, bk1, z, 0, 0, 0);
      s[nt] = z;
    }
#pragma unroll
    for (int nt = 0; nt < 4; ++nt) {
      int ko = ko0 + nt * 16 + l15;
      bool msk = (!INV) && (ko >= len);
#pragma unroll
      for (int r = 0; r < 4; ++r) {
        int qi = qw + quad * 4 + r;
        int dist = (q0 + qi) - ko;
        dist = min(max(dist, -(MPc - 1)), MPc - 1);
        float rv = us2f(Rqu[(rqrow + qi) * 384 + dist + 191]);
        s[nt][r] = msk ? NEGB : (s[nt][r] + rv);
      }
    }
#pragma unroll
    for (int r = 0; r < 4; ++r) {
      float mx = fmaxf(fmaxf(s[0][r], s[1][r]), fmaxf(s[2][r], s[3][r]));
#pragma unroll
      for (int o = 1; o < 16; o <<= 1) mx = fmaxf(mx, __shfl_xor(mx, o, 64));
      float mn = fmaxf(m_[r], mx);
      alpha[r] = __expf(m_[r] - mn);
      float p0 = __expf(s[0][r] - mn), p1 = __expf(s[1][r] - mn);
      float p2 = __expf(s[2][r] - mn), p3 = __expf(s[3][r] - mn);
      s[0][r] = p0; s[1][r] = p1; s[2][r] = p2; s[3][r] = p3;
      float ps = p0 + p1 + p2 + p3;
#pragma unroll
      for (int o = 1; o < 16; o <<= 1) ps += __shfl_xor(ps, o, 64);
      l_[r] = l_[r] * alpha[r] + ps;
      m_[r] = mn;
    }
#pragma unroll
    for (int nt = 0; nt < 4; ++nt)
#pragma unroll
      for (int r = 0; r < 4; ++r)
        Ps[(qw + quad * 4 + r) * 72 + nt * 16 + l15] = f2us(s[nt][r]);
#pragma unroll
    for (int j = 0; j < 4; ++j)
#pragma unroll
      for (int r = 0; r < 4; ++r) acc[j][r] *= alpha[r];
    short8 ap0 = *(short8*)&Ps[(qw + l15) * 72 + quad * 8];
    short8 ap1 = *(short8*)&Ps[(qw + l15) * 72 + 32 + quad * 8];
#pragma unroll
    for (int j = 0; j < 4; ++j) {
      short8 bv0 = *(short8*)&Vt[(j * 16 + l15) * 72 + quad * 8];
      short8 bv1 = *(short8*)&Vt[(j * 16 + l15) * 72 + 32 + quad * 8];
      acc[j] = __builtin_amdgcn_mfma_f32_16x16x32_bf16(ap0, bv0, acc[j], 0, 0, 0);
      acc[j] = __builtin_amdgcn_mfma_f32_16x16x32_bf16(ap1, bv1, acc[j], 0, 0, 0);
    }
  }
#pragma unroll
  for (int r = 0; r < 4; ++r) {
    int qi = qw + quad * 4 + r;
    bool wr = INV ? (qi >= nskip) : (qi < nvalid);
    if (wr) {
      float inv = 1.0f / l_[r];
#pragma unroll
      for (int j = 0; j < 4; ++j)
        out[((long)(b * Tc + q0 + qi)) * Dc + h * 64 + j * 16 + l15] = f2us(acc[j][r] * inv);
    }
  }
}

// ---------------- depthwise conv(9, pad4) + silu ----------------
__global__ void k_dwconv(const ushort_t* __restrict__ in, const ushort_t* __restrict__ dw,
                         ushort_t* __restrict__ out, int n) {
  int i = blockIdx.x * 256 + threadIdx.x;
  if (i >= n) return;
  int d = i & 511;
  int t = (i >> 9) & (Tc - 1);
  int b = i >> 19;
  float acc = 0.0f;
#pragma unroll
  for (int j = 0; j < 9; ++j) {
    int tt = t + j - 4;
    if (tt >= 0 && tt < Tc) acc += us2f(in[((long)(b * Tc + tt)) * 512 + d]) * us2f(dw[d * 9 + j]);
  }
  out[i] = f2us(acc * (1.0f / (1.0f + __expf(-acc))));
}

extern "C" void kernel_launch(void* const* d_in, const int* in_sizes, int n_in,
                              void* d_out, int out_size, void* d_ws, size_t ws_size,
                              hipStream_t stream) {
  const void* x_in = d_in[0];
  const int*  alen = (const int*)d_in[1];
  const void* ln1w = d_in[2];
  const void* ln1b = d_in[3];
  const void* wq   = d_in[4];
  const void* wk   = d_in[5];
  const void* wv   = d_in[6];
  const void* wo   = d_in[7];
  const void* rel  = d_in[8];
  const void* ln2w = d_in[9];
  const void* ln2b = d_in[10];
  const void* pw1  = d_in[11];
  const void* dwv  = d_in[12];
  const void* pw2  = d_in[13];
  const void* ln3w = d_in[14];
  const void* ln3b = d_in[15];
  const void* w1   = d_in[16];
  const void* w2   = d_in[17];

  char* base = (char*)d_ws;
  int*      flag = (int*)base;                       // 256
  float*    xf   = (float*)(base + 256);             // 8 MB
  float*    lnb  = (float*)(base + 256 + 8388608);   // 8 MB
  ushort_t* lnA  = (ushort_t*)(base + 16777472);     // 4 MB
  ushort_t* wbf  = (ushort_t*)(base + 20971776);     // 24,350,208 B
  char*     U    = base + 45321984;
  // attn phase
  ushort_t* qb = (ushort_t*)U;                       // 4 MB
  ushort_t* kb = (ushort_t*)(U + 4194304);           // 1 MB
  ushort_t* vb = (ushort_t*)(U + 5242880);           // 1 MB
  ushort_t* ab = (ushort_t*)(U + 6291456);           // 4 MB
  bf16*     Rq = (bf16*)(U + 10485760);              // 24 MB
  // conv phase
  ushort_t* gl = (ushort_t*)U;                       // 4 MB
  ushort_t* cb = (ushort_t*)(U + 4194304);           // 4 MB
  // ffn phase
  ushort_t* sw = (ushort_t*)U;                       // 8 MB
  size_t REQ = 45321984 + 35651584;
  if (ws_size < REQ) return;

  ushort_t* wqkvB = wbf + 0;            // [L][768][512], q rows pre-scaled 0.125
  ushort_t* woB   = wbf + 1572864;
  ushort_t* relB  = wbf + 2621440;
  ushort_t* pw1B  = wbf + 2719488;
  ushort_t* dwB   = wbf + 4816640;
  ushort_t* pw2B  = wbf + 4835072;
  ushort_t* w1B   = wbf + 5883648;
  ushort_t* w2B   = wbf + 10077952;

  k_detect<<<1, 256, 0, stream>>>(x_in, flag);
  k_in<<<(int)((NE + 255) / 256), 256, 0, stream>>>(x_in, xf, (int)NE, flag);
  for (int l = 0; l < 4; ++l) {
    k_w2b<<<1024, 256, 0, stream>>>(wq, (long)l * 262144, wqkvB + (long)l * 393216, 262144, 0.125f, flag);
    k_w2b<<<256,  256, 0, stream>>>(wk, (long)l * 65536, wqkvB + (long)l * 393216 + 262144, 65536, 1.0f, flag);
    k_w2b<<<256,  256, 0, stream>>>(wv, (long)l * 65536, wqkvB + (long)l * 393216 + 327680, 65536, 1.0f, flag);
  }
  k_w2b<<<4096, 256, 0, stream>>>(wo,  0, woB,  1048576, 1.0f, flag);
  k_w2b<<<383,  256, 0, stream>>>(rel, 0, relB, 98048, 1.0f, flag);
  k_w2b<<<8192, 256, 0, stream>>>(pw1, 0, pw1B, 2097152, 1.0f, flag);
  k_w2b<<<72,   256, 0, stream>>>(dwv, 0, dwB,  18432, 1.0f, flag);
  k_w2b<<<4096, 256, 0, stream>>>(pw2, 0, pw2B, 1048576, 1.0f, flag);
  k_w2b<<<16384,256, 0, stream>>>(w1,  0, w1B,  4194304, 1.0f, flag);
  k_w2b<<<8192, 256, 0, stream>>>(w2,  0, w2B,  2097152, 1.0f, flag);

  for (int i = 0; i < 4; ++i) {
    long oLN = (long)i * Dc;
    // ---- attention ----
    k_ln<<<NBT, 256, 0, stream>>>(xf, ln1w, ln1b, oLN, lnb, lnA, flag);
    k_gemm_qkv<<<dim3(6, 64), 256, 0, stream>>>(lnA, wqkvB + (long)i * 393216, qb, kb, vb, 512);
    k_rq_b<<<dim3(3, 8, 32), 256, 0, stream>>>(qb, relB + (long)i * 24512, Rq);
    k_attn_flash<false><<<dim3(16, 8, 4), 256, 0, stream>>>(qb, kb, vb, Rq, alen, ab);
    k_attn_flash<true><<<dim3(16, 8, 4), 256, 0, stream>>>(qb, kb, vb, Rq, alen, ab);
    k_gemm_b<64, 128, false><<<dim3(4, 64), 256, 0, stream>>>(ab, Dc, woB + (long)i * 262144, xf, Dc, lnb, 1.0f, 512);

    // ---- conv ----
    k_ln<<<NBT, 256, 0, stream>>>(xf, ln2w, ln2b, oLN, lnb, lnA, flag);
    k_gemm_glu<false><<<dim3(4, 64), 256, 0, stream>>>(lnA, pw1B + (long)i * 524288, gl, 512, 512);
    k_dwconv<<<NBT * 512 / 256, 256, 0, stream>>>(gl, dwB + (long)i * 4608, cb, NBT * 512);
    k_gemm_b<64, 128, false><<<dim3(4, 64), 256, 0, stream>>>(cb, Dc, pw2B + (long)i * 262144, xf, Dc, lnb, 1.0f, 512);

    // ---- ffn ----
    k_ln<<<NBT, 256, 0, stream>>>(xf, ln3w, ln3b, oLN, lnb, lnA, flag);
    k_gemm_glu<true><<<dim3(8, 64), 256, 0, stream>>>(lnA, w1B + (long)i * 1048576, sw, 1024, 512);
    k_gemm_b<64, 128, false><<<dim3(4, 64), 256, 0, stream>>>(sw, 1024, w2B + (long)i * 524288, xf, Dc, lnb, 1.0f, 1024);
  }

  k_out<<<(int)((NE + 255) / 256), 256, 0, stream>>>(xf, d_out, (int)NE, flag);
}